// Round 2
// baseline (568.596 us; speedup 1.0000x reference)
//
#include <hip/hip_runtime.h>

// MLP_RSNA6: B=500000 rows x 200 fp32 in; 25 groups x 8 contiguous cols ->
// dot(w1)+b1 -> relu -> h -> 3 outs (h*w2[t]+b2[t]) into 3 contiguous out
// cols; out = (B,75) fp32.
//
// Memory-bound: 400 MB read + 150 MB write -> ~87 us @ 6.3 TB/s achievable.
//
// R1 post-mortem: thread-per-(b,g) made every VMEM op strided (16B@32B-stride
// loads, 4B@12B-stride stores) -> 2-3x transaction amplification. R2: stage
// 32 rows/block through LDS so ALL global traffic is contiguous float4
// streams; the strided per-group access pattern hits LDS instead (69 TB/s,
// conflicts irrelevant at our BW level).
//
// LDS: 32*200*4 + 32*75*4 + idx = 35.4 KB -> 4 blocks/CU.
// Assumes in_out_k/in_out_v group bases are 4-aligned (arange in this
// problem; verified by R1 pass).

#define GROUPS  25
#define IN_NUM  8
#define ROW     200
#define OUTROW  75
#define OUTT    3
#define RPB     32          // rows per block
#define THREADS 256

__global__ __launch_bounds__(THREADS) void mlp_rsna6_kernel(
    const float* __restrict__ x,
    const float* __restrict__ w1,
    const float* __restrict__ b1,
    const float* __restrict__ w2,
    const float* __restrict__ b2,
    const int*   __restrict__ iok,
    const int*   __restrict__ iov,
    float*       __restrict__ out,
    int nrows)
{
    __shared__ float xs[RPB * ROW];      // 25600 B
    __shared__ float os[RPB * OUTROW];   //  9600 B
    __shared__ int   kb_s[GROUPS];
    __shared__ int   vb_s[GROUPS];

    const int tid = threadIdx.x;
    const int r0  = blockIdx.x * RPB;
    const int rows = min(RPB, nrows - r0);

    // ---- preload group base indices (once per block) ----
    if (tid < GROUPS) {
        kb_s[tid] = iok[tid * IN_NUM];
        vb_s[tid] = iov[tid * OUTT];
    }

    // ---- phase 1: global -> LDS, contiguous float4 stream ----
    // base byte addr = r0*800, multiple of 16 -> float4 ok.
    const float4* xg  = reinterpret_cast<const float4*>(x + (size_t)r0 * ROW);
    float4*       xs4 = reinterpret_cast<float4*>(xs);
    const int n4 = rows * (ROW / 4);                 // 1600 when full
    for (int i = tid; i < n4; i += THREADS) xs4[i] = xg[i];

    // ---- hoist uniform weights (scalar loads) ----
    const float W10 = w1[0], W11 = w1[1], W12 = w1[2], W13 = w1[3];
    const float W14 = w1[4], W15 = w1[5], W16 = w1[6], W17 = w1[7];
    const float B1  = b1[0];
    const float W20 = w2[0], W21 = w2[1], W22 = w2[2];
    const float B20 = b2[0], B21 = b2[1], B22 = b2[2];

    __syncthreads();

    // ---- phase 2: compute 800 (row,group) items out of LDS ----
    const int items = rows * GROUPS;
    for (int i = tid; i < items; i += THREADS) {
        int bl = i / GROUPS;
        int g  = i - bl * GROUPS;
        int kb = kb_s[g];
        int vb = vb_s[g];

        const float4* xp = reinterpret_cast<const float4*>(&xs[bl * ROW + kb]);
        float4 a0 = xp[0];
        float4 a1 = xp[1];

        float s = B1;
        s = fmaf(a0.x, W10, s);
        s = fmaf(a0.y, W11, s);
        s = fmaf(a0.z, W12, s);
        s = fmaf(a0.w, W13, s);
        s = fmaf(a1.x, W14, s);
        s = fmaf(a1.y, W15, s);
        s = fmaf(a1.z, W16, s);
        s = fmaf(a1.w, W17, s);
        float h = fmaxf(s, 0.0f);

        float* op = &os[bl * OUTROW + vb];
        op[0] = fmaf(h, W20, B20);
        op[1] = fmaf(h, W21, B21);
        op[2] = fmaf(h, W22, B22);
    }

    __syncthreads();

    // ---- phase 3: LDS -> global, contiguous float4 stream ----
    // base byte addr = r0*300, multiple of 16 when r0 % 4 == 0 (r0 = 32k).
    float4*       og  = reinterpret_cast<float4*>(out + (size_t)r0 * OUTROW);
    const float4* os4 = reinterpret_cast<const float4*>(os);
    const int fl  = rows * OUTROW;                   // 2400 when full
    const int m4  = fl / 4;                          // 600 when full
    for (int i = tid; i < m4; i += THREADS) og[i] = os4[i];
    // scalar tail (only possible in a partial last block)
    for (int i = m4 * 4 + tid; i < fl; i += THREADS)
        out[(size_t)r0 * OUTROW + i] = os[i];
}

extern "C" void kernel_launch(void* const* d_in, const int* in_sizes, int n_in,
                              void* d_out, int out_size, void* d_ws, size_t ws_size,
                              hipStream_t stream) {
    const float* x   = (const float*)d_in[0];
    const float* w1  = (const float*)d_in[1];
    const float* b1  = (const float*)d_in[2];
    const float* w2  = (const float*)d_in[3];
    const float* b2  = (const float*)d_in[4];
    const int*   iok = (const int*)d_in[5];
    const int*   iov = (const int*)d_in[6];
    float*       out = (float*)d_out;

    int nrows = in_sizes[0] / ROW;                  // 500000
    int grid  = (nrows + RPB - 1) / RPB;            // 15625
    mlp_rsna6_kernel<<<grid, THREADS, 0, stream>>>(
        x, w1, b1, w2, b2, iok, iov, out, nrows);
}